// Round 3
// baseline (824.769 us; speedup 1.0000x reference)
//
#include <hip/hip_runtime.h>

#define D 32
#define BSHIFT 7                 // 128 nodes per bucket
#define BNODES 128
#define NB_MAX 1024              // supports N <= 131072
#define ACHUNK 16384             // edges per bucketing block
#define ATHREADS 512
#define SCHUNK 1024

// ---------------------------------------------------------------------------
// K1: src_feat = feat @ Ws^T ; dst_feat = feat @ Wd^T + bd
// ---------------------------------------------------------------------------
__global__ __launch_bounds__(256) void k_node_transform(
    const float* __restrict__ feat, const float* __restrict__ Ws,
    const float* __restrict__ Wd, const float* __restrict__ bd,
    float* __restrict__ src_feat, float* __restrict__ dst_feat, int N)
{
    __shared__ float WsT[D * D];
    __shared__ float WdT[D * D];
    __shared__ float bdS[D];
    __shared__ float fS[8][D];

    const int t = threadIdx.x;
    for (int i = t; i < D * D; i += 256) {
        const int d = i >> 5, k = i & 31;
        WsT[k * D + d] = Ws[i];
        WdT[k * D + d] = Wd[i];
    }
    if (t < D) bdS[t] = bd[t];

    const int nodeBase = blockIdx.x * 8;
    {
        const int n = nodeBase + (t >> 5);
        fS[t >> 5][t & 31] = (n < N) ? feat[nodeBase * D + t] : 0.f;
    }
    __syncthreads();

    const int nl = t >> 5, d = t & 31;
    const int n = nodeBase + nl;
    if (n >= N) return;

    float accS = 0.f, accD = bdS[d];
#pragma unroll
    for (int k = 0; k < D; ++k) {
        const float f = fS[nl][k];
        accS += f * WsT[k * D + d];
        accD += f * WdT[k * D + d];
    }
    src_feat[n * D + d] = accS;
    dst_feat[n * D + d] = accD;
}

// ---------------------------------------------------------------------------
// A1: per-block LDS histogram of dst-buckets -> cnt[b * nblkA + blk]
// (covers every entry, so no global memset needed)
// ---------------------------------------------------------------------------
__global__ __launch_bounds__(ATHREADS) void k_histA(
    const int* __restrict__ dst, int* __restrict__ cnt,
    int E, int NB, int nblkA)
{
    __shared__ int h[NB_MAX];
    const int t = threadIdx.x;
    for (int i = t; i < NB; i += ATHREADS) h[i] = 0;
    __syncthreads();
    const int base = blockIdx.x * ACHUNK;
    const int end = min(base + ACHUNK, E);
    for (int e = base + t; e < end; e += ATHREADS)
        atomicAdd(&h[dst[e] >> BSHIFT], 1);
    __syncthreads();
    for (int b = t; b < NB; b += ATHREADS)
        cnt[b * nblkA + blockIdx.x] = h[b];
}

// --------------------------- exclusive scan trio ---------------------------
__global__ __launch_bounds__(256) void k_scan1(
    const int* __restrict__ in, int* __restrict__ out,
    int* __restrict__ bsums, int L)
{
    __shared__ int buf[2][SCHUNK];
    const int t = threadIdx.x;
    const int base = blockIdx.x * SCHUNK;
    for (int j = t; j < SCHUNK; j += 256)
        buf[0][j] = (base + j < L) ? in[base + j] : 0;
    __syncthreads();
    int pin = 0;
    for (int off = 1; off < SCHUNK; off <<= 1) {
        for (int j = t; j < SCHUNK; j += 256)
            buf[pin ^ 1][j] = buf[pin][j] + (j >= off ? buf[pin][j - off] : 0);
        __syncthreads();
        pin ^= 1;
    }
    for (int j = t; j < SCHUNK; j += 256)
        if (base + j < L) out[base + j] = (j > 0) ? buf[pin][j - 1] : 0;
    if (t == 0) bsums[blockIdx.x] = buf[pin][SCHUNK - 1];
}

__global__ __launch_bounds__(64) void k_scan2(int* __restrict__ bs, int nb)
{
    if (threadIdx.x == 0) {
        int run = 0;
        for (int i = 0; i < nb; ++i) { const int v = bs[i]; bs[i] = run; run += v; }
    }
}

__global__ __launch_bounds__(256) void k_scan3(
    int* __restrict__ out, const int* __restrict__ bsums, int L)
{
    const int i = blockIdx.x * 256 + threadIdx.x;
    if (i < L) out[i] += bsums[i >> 10];
}

// ---------------------------------------------------------------------------
// A2: rank edges via fresh LDS counters; write ONE packed int per edge:
//     (vloc << 20) | u.  Slots for a given (block,bucket) are consecutive
//     (~21-slot runs), so dirty lines are mostly single-owner.
// ---------------------------------------------------------------------------
__global__ __launch_bounds__(ATHREADS) void k_scatA(
    const int* __restrict__ src, const int* __restrict__ dst,
    const int* __restrict__ off, int* __restrict__ edge_pk,
    int E, int NB, int nblkA)
{
    __shared__ int h[NB_MAX];
    const int t = threadIdx.x;
    for (int i = t; i < NB; i += ATHREADS) h[i] = 0;
    __syncthreads();
    const int base = blockIdx.x * ACHUNK;
    const int end = min(base + ACHUNK, E);
    for (int e = base + t; e < end; e += ATHREADS) {
        const int v = dst[e];
        const int b = v >> BSHIFT;
        const int r = atomicAdd(&h[b], 1);
        const int pos = off[b * nblkA + blockIdx.x] + r;
        edge_pk[pos] = src[e] | ((v & (BNODES - 1)) << 20);
    }
}

// ---------------------------------------------------------------------------
// B: one workgroup per bucket (128 nodes). LDS-accumulated aggregation
//    (ds_add_f32, lane d -> bank d, conflict-free) + deg*dst_feat +
//    out = agg@Wr^T+br ; src2 = out@Ws^T ; dst2 = out@Wd^T+bd.
//    Zero global atomics.
// ---------------------------------------------------------------------------
__global__ __launch_bounds__(256) void k_aggB(
    const int* __restrict__ edge_pk, const int* __restrict__ off,
    const float* __restrict__ src_feat, const float* __restrict__ dst_feat,
    const float* __restrict__ Ws, const float* __restrict__ Wd,
    const float* __restrict__ bd, const float* __restrict__ Wr,
    const float* __restrict__ br,
    float* __restrict__ src2, float* __restrict__ dst2,
    int N, int E, int NB, int nblkA)
{
    __shared__ float agg[BNODES][D];    // 16 KB
    __shared__ float oAll[BNODES][D];   // 16 KB
    __shared__ float WsT[D * D];        // 4 KB
    __shared__ float WdT[D * D];        // 4 KB
    __shared__ float WrT[D * D];        // 4 KB
    __shared__ float bdS[D], brS[D];
    __shared__ int degS[BNODES];        // 0.5 KB

    const int t = threadIdx.x;
    const int b = blockIdx.x;

    for (int i = t; i < D * D; i += 256) {
        const int d = i >> 5, k = i & 31;
        WsT[k * D + d] = Ws[i];
        WdT[k * D + d] = Wd[i];
        WrT[k * D + d] = Wr[i];
    }
    if (t < D) { bdS[t] = bd[t]; brS[t] = br[t]; }
    for (int i = t; i < BNODES * D; i += 256) ((float*)agg)[i] = 0.f;
    for (int i = t; i < BNODES; i += 256) degS[i] = 0;
    __syncthreads();

    const int eStart = off[b * nblkA];
    const int eEnd   = (b == NB - 1) ? E : off[(b + 1) * nblkA];

    const int g = t >> 5, lane = t & 31;       // 8 edge-groups of 32 lanes
    for (int i = eStart + g; i < eEnd; i += 8) {
        const int p = edge_pk[i];
        const int u = p & 0xFFFFF;
        const int vloc = p >> 20;
        atomicAdd(&agg[vloc][lane], src_feat[u * D + lane]);
        if (lane == 0) atomicAdd(&degS[vloc], 1);
    }
    __syncthreads();

    const int nodeBase = b << BSHIFT;

    // agg += deg * dst_feat
    for (int p = 0; p < BNODES / 8; ++p) {
        const int nloc = p * 8 + g;
        const int n = nodeBase + nloc;
        if (n < N)
            agg[nloc][lane] += (float)degS[nloc] * dst_feat[n * D + lane];
    }
    __syncthreads();

    // out = agg @ Wr^T + br   (agg row reads are broadcast)
    for (int p = 0; p < BNODES / 8; ++p) {
        const int nloc = p * 8 + g;
        float o = brS[lane];
#pragma unroll
        for (int k = 0; k < D; ++k) o += agg[nloc][k] * WrT[k * D + lane];
        oAll[nloc][lane] = o;
    }
    __syncthreads();

    // src2 = out @ Ws^T ; dst2 = out @ Wd^T + bd
    for (int p = 0; p < BNODES / 8; ++p) {
        const int nloc = p * 8 + g;
        const int n = nodeBase + nloc;
        if (n >= N) continue;
        float s = 0.f, dd = bdS[lane];
#pragma unroll
        for (int k = 0; k < D; ++k) {
            const float ov = oAll[nloc][k];
            s  += ov * WsT[k * D + lane];
            dd += ov * WdT[k * D + lane];
        }
        src2[n * D + lane] = s;
        dst2[n * D + lane] = dd;
    }
}

// ---------------------------------------------------------------------------
// K4: out[e] = src2[src[e]] + dst2[dst[e]]   ([E, 32] f32, coalesced float4)
// ---------------------------------------------------------------------------
__global__ __launch_bounds__(256) void k_gather_out(
    const int* __restrict__ src, const int* __restrict__ dst,
    const float* __restrict__ src2, const float* __restrict__ dst2,
    float* __restrict__ out, int E)
{
    const long g = (long)blockIdx.x * 256 + threadIdx.x;
    const int e = (int)(g >> 3);
    if (e >= E) return;
    const int q = (int)(g & 7);

    const int u = src[e], v = dst[e];
    const float4 a = *(const float4*)(src2 + u * D + q * 4);
    const float4 b = *(const float4*)(dst2 + v * D + q * 4);
    float4 r;
    r.x = a.x + b.x; r.y = a.y + b.y; r.z = a.z + b.z; r.w = a.w + b.w;
    *(float4*)(out + (long)e * D + q * 4) = r;
}

extern "C" void kernel_launch(void* const* d_in, const int* in_sizes, int n_in,
                              void* d_out, int out_size, void* d_ws, size_t ws_size,
                              hipStream_t stream)
{
    const float* feat = (const float*)d_in[0];
    const int*   src  = (const int*)d_in[1];
    const int*   dst  = (const int*)d_in[2];
    const float* Ws   = (const float*)d_in[3];
    const float* Wd   = (const float*)d_in[4];
    const float* bd   = (const float*)d_in[5];
    const float* Wr   = (const float*)d_in[6];
    const float* br   = (const float*)d_in[7];
    float* out = (float*)d_out;

    const int N = in_sizes[0] / D;
    const int E = in_sizes[1];

    const int NB    = (N + BNODES - 1) >> BSHIFT;          // 782
    const int nblkA = (E + ACHUNK - 1) / ACHUNK;           // 98
    const int L     = NB * nblkA;                          // 76,636
    const int nbScan = (L + SCHUNK - 1) / SCHUNK;          // 75

    const size_t nodeBytes = (size_t)N * D * sizeof(float);

    // Scratch dead before the final kernel lives at the front of d_out
    // (204.8 MB, fully overwritten by k_gather_out). src2/dst2 (read during
    // the final kernel) live in d_ws.
    char* ob = (char*)d_out;
    float* src_feat = (float*)ob;                              // 12.8 MB
    float* dst_feat = (float*)(ob + nodeBytes);                // 12.8 MB
    int*   edge_pk  = (int*)(ob + 2 * nodeBytes);              //  6.4 MB
    int*   cnt      = (int*)(ob + 2 * nodeBytes + (size_t)E * 4);
    int*   off      = cnt + L;
    int*   bsums    = off + L;

    float* src2 = (float*)d_ws;
    float* dst2 = (float*)((char*)d_ws + nodeBytes);

    const int nodeBlocks = (N + 7) / 8;

    k_node_transform<<<nodeBlocks, 256, 0, stream>>>(feat, Ws, Wd, bd,
                                                     src_feat, dst_feat, N);

    k_histA<<<nblkA, ATHREADS, 0, stream>>>(dst, cnt, E, NB, nblkA);
    k_scan1<<<nbScan, 256, 0, stream>>>(cnt, off, bsums, L);
    k_scan2<<<1, 64, 0, stream>>>(bsums, nbScan);
    k_scan3<<<(L + 255) / 256, 256, 0, stream>>>(off, bsums, L);
    k_scatA<<<nblkA, ATHREADS, 0, stream>>>(src, dst, off, edge_pk, E, NB, nblkA);

    k_aggB<<<NB, 256, 0, stream>>>(edge_pk, off, src_feat, dst_feat,
                                   Ws, Wd, bd, Wr, br, src2, dst2,
                                   N, E, NB, nblkA);

    const long outThreads = (long)E * 8;
    const int outBlocks = (int)((outThreads + 255) / 256);
    k_gather_out<<<outBlocks, 256, 0, stream>>>(src, dst, src2, dst2, out, E);
}